// Round 10
// baseline (179.044 us; speedup 1.0000x reference)
//
#include <hip/hip_runtime.h>

#define GCN_N 100000
#define GCN_H 128
#define GCN_G 256
#define NPB_SHIFT 9                    // 512 nodes per bucket
#define NPB 512
#define NBKT 196                       // ceil(100000/512)
#define CHUNK 2048                     // edges per hist/partition block
#define SRC_BITS 17
#define SRC_MASK ((1 << SRC_BITS) - 1)
#define EBUF_CAP 10240                 // LDS staging for csr_build

static_assert(GCN_N < (1 << SRC_BITS), "src id must fit 17 bits");

using short8 = __attribute__((ext_vector_type(8))) short;
using f32x4  = __attribute__((ext_vector_type(4))) float;
using f32x2  = __attribute__((ext_vector_type(2))) float;

#if defined(__has_builtin)
#if __has_builtin(__builtin_amdgcn_cvt_scalef32_pk_f32_fp4)
#define HW_FP4 1
#endif
#endif

// ---------------- bf16 / fp4 helpers ----------------

__device__ __forceinline__ unsigned short f2bf(float f) {
    unsigned u = __float_as_uint(f);
    unsigned r = u + 0x7FFFu + ((u >> 16) & 1u);   // round to nearest even
    return (unsigned short)(r >> 16);
}
__device__ __forceinline__ float bf2f(unsigned short h) {
    return __uint_as_float(((unsigned)h) << 16);
}

// decode 8 fp4(e2m1) packed in a dword -> 8 floats (unscaled)
__device__ __forceinline__ void fp4x8_to_f32(unsigned v, float* f) {
#ifdef HW_FP4
    f32x2 p0 = __builtin_amdgcn_cvt_scalef32_pk_f32_fp4(v, 1.0f, 0);
    f32x2 p1 = __builtin_amdgcn_cvt_scalef32_pk_f32_fp4(v, 1.0f, 1);
    f32x2 p2 = __builtin_amdgcn_cvt_scalef32_pk_f32_fp4(v, 1.0f, 2);
    f32x2 p3 = __builtin_amdgcn_cvt_scalef32_pk_f32_fp4(v, 1.0f, 3);
    f[0] = p0[0]; f[1] = p0[1]; f[2] = p1[0]; f[3] = p1[1];
    f[4] = p2[0]; f[5] = p2[1]; f[6] = p3[0]; f[7] = p3[1];
#else
    #pragma unroll
    for (int j = 0; j < 8; j++) {
        unsigned nib = (v >> (4 * j)) & 0xF;
        unsigned e = (nib >> 1) & 3, m = nib & 1;
        float mag = (e == 0) ? 0.5f * (float)m : ldexpf(1.0f + 0.5f * (float)m, (int)e - 1);
        f[j] = (nib & 8) ? -mag : mag;
    }
#endif
}

// encode v/scale (|v/scale|<=6) to e2m1 nibble (software, semantics-safe)
__device__ __forceinline__ unsigned f32_to_fp4(float a) {
    unsigned sg = (a < 0.f) ? 8u : 0u;
    float b = fabsf(a);
    unsigned q = (unsigned)(b >= 0.25f) + (unsigned)(b >= 0.75f) + (unsigned)(b >= 1.25f)
               + (unsigned)(b >= 1.75f) + (unsigned)(b >= 2.5f) + (unsigned)(b >= 3.5f)
               + (unsigned)(b >= 5.0f);
    return sg | q;
}

// ---------------- hist + prep (fused) ----------------
// blocks [0,B): per-block dst histogram; [B,B+64): W1^T->bf16; B+64: w2l+c2

__global__ __launch_bounds__(256) void hist_prep_kernel(const int* __restrict__ dst,
                                                        int* __restrict__ hist, int E, int B,
                                                        const float* __restrict__ W1,
                                                        const float* __restrict__ W2,
                                                        const float* __restrict__ b2,
                                                        const float* __restrict__ lw,
                                                        unsigned short* __restrict__ w1t,
                                                        float* __restrict__ w2l,
                                                        float* __restrict__ c2) {
    __shared__ int lh[NBKT];
    __shared__ float slw[128];
    int blk = blockIdx.x, tid = threadIdx.x;
    if (blk < B) {
        if (tid < NBKT) lh[tid] = 0;
        __syncthreads();
        int e0 = blk * CHUNK;
        #pragma unroll
        for (int i = 0; i < CHUNK / 256; i++) {
            int e = e0 + tid + i * 256;
            if (e < E) atomicAdd(&lh[dst[e] >> NPB_SHIFT], 1);
        }
        __syncthreads();
        if (tid < NBKT) hist[(size_t)blk * NBKT + tid] = lh[tid];
    } else if (blk < B + 64) {
        int idx = (blk - B) * 256 + tid;           // 0..16383
        int col = idx >> 7, k = idx & 127;
        w1t[idx] = f2bf(W1[k * 128 + col]);
    } else {
        if (tid < 128) slw[tid] = lw[tid];
        __syncthreads();
        if (tid < 128) {
            float s = 0.f;
            #pragma unroll 8
            for (int j = 0; j < 128; j++) s = fmaf(W2[tid * 128 + j], slw[j], s);
            w2l[tid] = s;
        } else if (tid == 128) {
            float s = 0.f;
            for (int j = 0; j < 128; j++) s = fmaf(b2[j], slw[j], s);
            c2[0] = s;
        }
    }
}

__global__ __launch_bounds__(64) void scan_cols_kernel(const int* __restrict__ hist,
                                                       int* __restrict__ offsT,
                                                       int* __restrict__ btot, int B) {
    int k = blockIdx.x;
    int lane = threadIdx.x;
    int running = 0;
    for (int b0 = 0; b0 < B; b0 += 64) {
        int b = b0 + lane;
        int v = (b < B) ? hist[(size_t)b * NBKT + k] : 0;
        int iv = v;
        #pragma unroll
        for (int d = 1; d < 64; d <<= 1) {
            int x = __shfl_up(iv, d, 64);
            if (lane >= d) iv += x;
        }
        if (b < B) offsT[(size_t)k * B + b] = running + iv - v;   // exclusive
        running += __shfl(iv, 63, 64);
    }
    if (lane == 0) btot[k] = running;
}

// partition: recomputes bucket bases from btot in-block (no bucket_base kernel)
__global__ __launch_bounds__(256) void partition_kernel(const int* __restrict__ src,
                                                        const int* __restrict__ dst,
                                                        const int* __restrict__ btot,
                                                        const int* __restrict__ offsT,
                                                        int* __restrict__ epack,
                                                        int E, int B) {
    __shared__ int cur[NBKT];
    __shared__ int sbase[NBKT];
    int blk = blockIdx.x, tid = threadIdx.x;
    if (tid == 0) {
        int run = 0;
        for (int kk = 0; kk < NBKT; kk++) { sbase[kk] = run; run += btot[kk]; }
    }
    __syncthreads();
    if (tid < NBKT) cur[tid] = sbase[tid] + offsT[(size_t)tid * B + blk];
    __syncthreads();
    int e0 = blk * CHUNK;
    #pragma unroll
    for (int i = 0; i < CHUNK / 256; i++) {
        int e = e0 + tid + i * 256;
        if (e < E) {
            int d = dst[e];
            int s = src[e];
            int pos = atomicAdd(&cur[d >> NPB_SHIFT], 1);
            epack[pos] = ((d & (NPB - 1)) << SRC_BITS) | s;
        }
    }
}

// builds local CSR AND writes dis + xsp; LDS-stages its epack slice
__global__ __launch_bounds__(512) void csr_build_kernel(const int* __restrict__ epack,
                                                        const int* __restrict__ btot,
                                                        const float* __restrict__ x,
                                                        int* __restrict__ rowptr,
                                                        float* __restrict__ dis,
                                                        float* __restrict__ xsp,
                                                        int* __restrict__ csrc, int n) {
    __shared__ int ebuf[EBUF_CAP];              // 40 KB
    __shared__ int lcount[NPB];
    __shared__ int lcur[NPB];
    __shared__ int wsums[8];
    __shared__ int s_eb, s_ee, s_tot;
    int k = blockIdx.x, tid = threadIdx.x;
    int lane = tid & 63, wid = tid >> 6;
    int nodebase = k << NPB_SHIFT;

    lcount[tid] = 0;
    if (tid == 0) {
        int run = 0, eb = 0, ee = 0;
        for (int kk = 0; kk < NBKT; kk++) {
            if (kk == k) eb = run;
            run += btot[kk];
            if (kk == k) ee = run;
        }
        s_eb = eb; s_ee = ee; s_tot = run;
    }
    __syncthreads();
    int ebeg = s_eb, eend = s_ee;
    bool fits = (eend - ebeg) <= EBUF_CAP;

    for (int e = ebeg + tid; e < eend; e += 512) {
        int p = epack[e];
        if (fits) ebuf[e - ebeg] = p;
        atomicAdd(&lcount[p >> SRC_BITS], 1);
    }
    __syncthreads();

    int v = lcount[tid];
    int iv = v;
    #pragma unroll
    for (int d = 1; d < 64; d <<= 1) {
        int x2 = __shfl_up(iv, d, 64);
        if (lane >= d) iv += x2;
    }
    if (lane == 63) wsums[wid] = iv;
    __syncthreads();
    if (tid == 0) {
        int r = 0;
        #pragma unroll
        for (int w = 0; w < 8; w++) { int t = wsums[w]; wsums[w] = r; r += t; }
    }
    __syncthreads();
    int ex = wsums[wid] + iv - v;
    lcur[tid] = ex;
    int node = nodebase + tid;
    if (node < n) {
        rowptr[node] = ebeg + ex;
        float dd = rsqrtf((float)(v + 1));       // deg = indeg + self-loop
        dis[node] = dd;
        const float* xr = x + (size_t)node * 5;
        float4 a;
        a.x = xr[0] * dd; a.y = xr[1] * dd; a.z = xr[2] * dd; a.w = xr[3] * dd;
        float a4 = xr[4] * dd;
        ((float4*)(xsp + (size_t)node * 8))[0] = a;
        xsp[(size_t)node * 8 + 4] = a4;
        xsp[(size_t)node * 8 + 5] = 0.f;
        xsp[(size_t)node * 8 + 6] = 0.f;
        xsp[(size_t)node * 8 + 7] = 0.f;
    }
    if (k == NBKT - 1 && tid == 0) rowptr[n] = s_tot;
    __syncthreads();
    for (int e = ebeg + tid; e < eend; e += 512) {
        int p = fits ? ebuf[e - ebeg] : epack[e];
        int pos = atomicAdd(&lcur[p >> SRC_BITS], 1);
        csrc[ebeg + pos] = p & SRC_MASK;
    }
}

// ------- fused aggx + mm (MFMA): t1 = fp4_rowscaled( dis ⊙ (relu(a0@W0+b0) @ W1) ) -------
// threads 0..127: 5-dim aggregation for this block's 128 nodes (a0 rows into LDS)
// threads 128..255: stage W1^T into LDS concurrently.

__global__ __launch_bounds__(256) void mmfused_kernel(const float* __restrict__ xsp,
                                                      const int* __restrict__ rowptr,
                                                      const int* __restrict__ csrc,
                                                      const float* __restrict__ W0,
                                                      const float* __restrict__ b0,
                                                      const unsigned short* __restrict__ w1t,
                                                      const float* __restrict__ dis,
                                                      unsigned* __restrict__ t1q4,
                                                      float* __restrict__ tscale, int n) {
    __shared__ __align__(16) unsigned short sA[128 * 128];   // 32 KB h1 / reused for out
    __shared__ __align__(16) unsigned short sBT[128 * 128];  // 32 KB W1^T
    __shared__ __align__(16) float sA0f[128 * 8];            // 4 KB a0 rows
    __shared__ float sDis[128];
    __shared__ float sSmax[128];
    char* sAb = (char*)sA;
    char* sBb = (char*)sBT;
    int tid = threadIdx.x;
    int rowBase = blockIdx.x * 128;

    if (tid < 128) {
        int i = rowBase + tid;
        float a[5] = {0.f, 0.f, 0.f, 0.f, 0.f};
        float di = 0.f;
        if (i < n) {
            di = dis[i];
            const float* xr = xsp + (size_t)i * 8;
            float4 s4 = ((const float4*)xr)[0];
            a[0] = s4.x; a[1] = s4.y; a[2] = s4.z; a[3] = s4.w; a[4] = xr[4];
            int r0 = rowptr[i], r1 = rowptr[i + 1];
            int e = r0;
            for (; e + 7 < r1; e += 8) {
                int ss[8];
                #pragma unroll
                for (int u = 0; u < 8; u++) ss[u] = csrc[e + u];
                float4 v[8]; float a4[8];
                #pragma unroll
                for (int u = 0; u < 8; u++) {
                    v[u] = ((const float4*)(xsp + (size_t)ss[u] * 8))[0];
                    a4[u] = xsp[(size_t)ss[u] * 8 + 4];
                }
                #pragma unroll
                for (int u = 0; u < 8; u++) {
                    a[0] += v[u].x; a[1] += v[u].y; a[2] += v[u].z; a[3] += v[u].w;
                    a[4] += a4[u];
                }
            }
            for (; e < r1; e++) {
                int s = csrc[e];
                float4 v = ((const float4*)(xsp + (size_t)s * 8))[0];
                a[0] += v.x; a[1] += v.y; a[2] += v.z; a[3] += v.w;
                a[4] += xsp[(size_t)s * 8 + 4];
            }
            #pragma unroll
            for (int j = 0; j < 5; j++) a[j] *= di;
        }
        sDis[tid] = di;
        #pragma unroll
        for (int j = 0; j < 5; j++) sA0f[tid * 8 + j] = a[j];
    } else {
        int t2 = tid - 128;
        #pragma unroll
        for (int it = 0; it < 16; it++) {
            int idx = t2 + it * 128;            // uint4 index, 0..2047
            int col = idx >> 4, c = idx & 15;
            uint4 v = ((const uint4*)w1t)[idx];
            int byteoff = (col * 256 + c * 16) ^ ((col & 7) << 4);
            *(uint4*)(sBb + byteoff) = v;
        }
    }
    __syncthreads();

    // h1 = relu(a0 @ W0 + b0) -> sA bf16, swizzled
    {
        int cq = tid & 31;
        int rg = tid >> 5;
        float4 w0q[5];
        #pragma unroll
        for (int j = 0; j < 5; j++) w0q[j] = *((const float4*)(W0 + j * 128 + cq * 4));
        float4 b0q = *((const float4*)(b0 + cq * 4));
        #pragma unroll
        for (int ri = 0; ri < 16; ri++) {
            int row = rg + ri * 8;
            const float* ar = sA0f + row * 8;
            float4 h = b0q;
            #pragma unroll
            for (int j = 0; j < 5; j++) {
                float aj = ar[j];
                h.x = fmaf(aj, w0q[j].x, h.x);
                h.y = fmaf(aj, w0q[j].y, h.y);
                h.z = fmaf(aj, w0q[j].z, h.z);
                h.w = fmaf(aj, w0q[j].w, h.w);
            }
            h.x = fmaxf(h.x, 0.f); h.y = fmaxf(h.y, 0.f);
            h.z = fmaxf(h.z, 0.f); h.w = fmaxf(h.w, 0.f);
            uint2 p;
            p.x = (unsigned)f2bf(h.x) | ((unsigned)f2bf(h.y) << 16);
            p.y = (unsigned)f2bf(h.z) | ((unsigned)f2bf(h.w) << 16);
            int byteoff = (row * 256 + cq * 8) ^ ((row & 7) << 4);
            *(uint2*)(sAb + byteoff) = p;
        }
    }
    __syncthreads();

    int wave = tid >> 6, l = tid & 63;
    int lr = l & 15, lg = l >> 4;
    int rb = wave * 32;

    short8 afr[2][4];
    #pragma unroll
    for (int rt = 0; rt < 2; rt++) {
        int row = rb + rt * 16 + lr;
        #pragma unroll
        for (int ks = 0; ks < 4; ks++) {
            int byteoff = (row * 256 + ks * 64 + lg * 16) ^ ((row & 7) << 4);
            afr[rt][ks] = *(const short8*)(sAb + byteoff);
        }
    }
    f32x4 acc[2][8];
    #pragma unroll
    for (int rt = 0; rt < 2; rt++)
        #pragma unroll
        for (int ct = 0; ct < 8; ct++)
            acc[rt][ct] = (f32x4){0.f, 0.f, 0.f, 0.f};

    #pragma unroll
    for (int ct = 0; ct < 8; ct++) {
        int col = ct * 16 + lr;
        short8 bfr[4];
        #pragma unroll
        for (int ks = 0; ks < 4; ks++) {
            int byteoff = (col * 256 + ks * 64 + lg * 16) ^ ((col & 7) << 4);
            bfr[ks] = *(const short8*)(sBb + byteoff);
        }
        #pragma unroll
        for (int rt = 0; rt < 2; rt++) {
            #pragma unroll
            for (int ks = 0; ks < 4; ks++) {
                acc[rt][ct] = __builtin_amdgcn_mfma_f32_16x16x32_bf16(
                    afr[rt][ks], bfr[ks], acc[rt][ct], 0, 0, 0);
            }
        }
    }

    // epilogue: dis-scale, bf16 into sA, per-row absmax via 16-lane shfl_xor reduce
    #pragma unroll
    for (int rt = 0; rt < 2; rt++) {
        #pragma unroll
        for (int i = 0; i < 4; i++) {
            int rowL = rb + rt * 16 + lg * 4 + i;
            float dsc = sDis[rowL];
            float m = 0.f;
            #pragma unroll
            for (int ct = 0; ct < 8; ct++) {
                int col = ct * 16 + lr;
                float vv = acc[rt][ct][i] * dsc;
                int byteoff = (rowL * 256 + col * 2) ^ ((rowL & 7) << 4);
                *(unsigned short*)(sAb + byteoff) = f2bf(vv);
                m = fmaxf(m, fabsf(vv));
            }
            #pragma unroll
            for (int msk = 1; msk < 16; msk <<= 1)
                m = fmaxf(m, __shfl_xor(m, msk, 64));
            if (lr == 0) sSmax[rowL] = m;
        }
    }
    __syncthreads();

    // copy-out: bf16 -> fp4 e2m1 with per-row scale; 8 cols -> 1 dword
    #pragma unroll
    for (int it = 0; it < 8; it++) {
        int flat = tid + it * 256;
        int rowL = flat >> 4, c16 = flat & 15;
        int gr = rowBase + rowL;
        if (gr < n) {
            int byteoff = (rowL * 256 + c16 * 16) ^ ((rowL & 7) << 4);
            uint4 v = *(const uint4*)(sAb + byteoff);
            float ff[8];
            ff[0] = __uint_as_float(v.x << 16); ff[1] = __uint_as_float(v.x & 0xFFFF0000u);
            ff[2] = __uint_as_float(v.y << 16); ff[3] = __uint_as_float(v.y & 0xFFFF0000u);
            ff[4] = __uint_as_float(v.z << 16); ff[5] = __uint_as_float(v.z & 0xFFFF0000u);
            ff[6] = __uint_as_float(v.w << 16); ff[7] = __uint_as_float(v.w & 0xFFFF0000u);
            float s6 = sSmax[rowL] * (1.f / 6.f);
            float inv = (s6 > 0.f) ? 1.f / s6 : 0.f;
            unsigned q = 0;
            #pragma unroll
            for (int j = 0; j < 8; j++) q |= f32_to_fp4(ff[j] * inv) << (4 * j);
            t1q4[(size_t)gr * 16 + c16] = q;
            if (c16 == 0) tscale[gr] = s6;
        }
    }
}

// --------- layer-1 aggregation (fp4 gather, 64 B/row) + layer-2 dot ---------

__global__ __launch_bounds__(256) void agg1_kernel(const unsigned* __restrict__ t1q4,
                                                   const float* __restrict__ tscale,
                                                   const float* __restrict__ dis,
                                                   const int* __restrict__ rowptr,
                                                   const int* __restrict__ csrc,
                                                   const float* __restrict__ b1,
                                                   const float* __restrict__ w2l,
                                                   float* __restrict__ z, int n) {
    int group = threadIdx.x >> 4, lane = threadIdx.x & 15;
    int i = blockIdx.x * 16 + group;
    if (i >= n) return;
    float f[8], acc[8];
    unsigned sv = t1q4[(size_t)i * 16 + lane];
    float sci = tscale[i];
    fp4x8_to_f32(sv, f);
    #pragma unroll
    for (int j = 0; j < 8; j++) acc[j] = f[j] * sci;
    int r0 = rowptr[i], r1 = rowptr[i + 1];
    for (int e = r0; e < r1; e += 16) {
        int cnt = r1 - e; if (cnt > 16) cnt = 16;   // uniform within group
        int idx = e + lane;
        int si = (idx < r1) ? csrc[idx] : 0;        // coalesced index load
        unsigned vv[16]; float sc[16];
        #pragma unroll
        for (int u = 0; u < 16; u++) {
            if (u < cnt) {
                int s = __shfl(si, u, 16);
                vv[u] = t1q4[(size_t)s * 16 + lane]; // one 64-B line per row
                sc[u] = tscale[s];
            }
        }
        #pragma unroll
        for (int u = 0; u < 16; u++) {
            if (u < cnt) {
                fp4x8_to_f32(vv[u], f);
                #pragma unroll
                for (int j = 0; j < 8; j++) acc[j] = fmaf(f[j], sc[u], acc[j]);
            }
        }
    }
    float di = dis[i];
    float4 b4a = ((const float4*)b1)[lane * 2];
    float4 b4b = ((const float4*)b1)[lane * 2 + 1];
    float4 w4a = ((const float4*)w2l)[lane * 2];
    float4 w4b = ((const float4*)w2l)[lane * 2 + 1];
    float bb[8] = {b4a.x, b4a.y, b4a.z, b4a.w, b4b.x, b4b.y, b4b.z, b4b.w};
    float ww[8] = {w4a.x, w4a.y, w4a.z, w4a.w, w4b.x, w4b.y, w4b.z, w4b.w};
    float d = 0.f;
    #pragma unroll
    for (int j = 0; j < 8; j++) {
        float c = fmaxf(fmaf(di, acc[j], bb[j]), 0.f);
        d = fmaf(c, ww[j], d);
    }
    #pragma unroll
    for (int o = 8; o > 0; o >>= 1) d += __shfl_down(d, o, 16);
    if (lane == 0) z[i] = di * d;
}

// ------- layer-2 scalar aggregation + pooling + FINAL (last-block) -------

__global__ __launch_bounds__(256) void aggz_pool_kernel(const float* __restrict__ z,
                                                        const float* __restrict__ dis,
                                                        const int* __restrict__ rowptr,
                                                        const int* __restrict__ csrc,
                                                        const int* __restrict__ batch,
                                                        const float* __restrict__ c2,
                                                        const float* __restrict__ lb,
                                                        float* __restrict__ gsum,
                                                        int* __restrict__ gcnt,
                                                        int* __restrict__ done,
                                                        float* __restrict__ out, int n) {
    __shared__ float lg[GCN_G];
    __shared__ int lc[GCN_G];
    __shared__ int sticket;
    int tid = threadIdx.x;
    lg[tid] = 0.f;
    lc[tid] = 0;
    __syncthreads();
    int i = blockIdx.x * 256 + tid;
    bool valid = i < n;
    float ndv = 0.f;
    int g = 0;
    if (valid) {
        float acc = z[i];
        int r0 = rowptr[i], r1 = rowptr[i + 1];
        int e = r0;
        for (; e + 7 < r1; e += 8) {
            int ss[8];
            #pragma unroll
            for (int u = 0; u < 8; u++) ss[u] = csrc[e + u];
            float zv[8];
            #pragma unroll
            for (int u = 0; u < 8; u++) zv[u] = z[ss[u]];
            #pragma unroll
            for (int u = 0; u < 8; u++) acc += zv[u];
        }
        for (; e < r1; e++) acc += z[csrc[e]];
        ndv = dis[i] * acc;
        g = batch[i];
    }
    int lane = tid & 63;
    int g0 = __shfl(g, 0, 64);
    bool uni = __all(g == g0) && __all(valid);
    if (uni) {
        float s = ndv;
        #pragma unroll
        for (int o = 32; o > 0; o >>= 1) s += __shfl_down(s, o, 64);
        if (lane == 0) {
            atomicAdd(&lg[g0], s);
            atomicAdd(&lc[g0], 64);
        }
    } else if (valid) {
        atomicAdd(&lg[g], ndv);
        atomicAdd(&lc[g], 1);
    }
    __syncthreads();
    float v = lg[tid];
    int c = lc[tid];
    if (v != 0.f) atomicAdd(&gsum[tid], v);
    if (c != 0) atomicAdd(&gcnt[tid], c);

    // last-block final: device-scope ticket + atomic reads
    __threadfence();
    if (tid == 0) sticket = atomicAdd(done, 1);
    __syncthreads();
    if (sticket == (int)gridDim.x - 1) {
        float sv = atomicAdd(&gsum[tid], 0.f);
        int cv = atomicAdd(&gcnt[tid], 0);
        float vv = sv / (float)max(cv, 1) + c2[0] + lb[0];
        out[tid] = 1.f / (1.f + expf(-vv));
    }
}

// ---------------- launch ----------------

extern "C" void kernel_launch(void* const* d_in, const int* in_sizes, int n_in,
                              void* d_out, int out_size, void* d_ws, size_t ws_size,
                              hipStream_t stream) {
    const float* x   = (const float*)d_in[0];
    const int*   ei  = (const int*)d_in[1];
    const int*   bat = (const int*)d_in[2];
    const float* W0  = (const float*)d_in[3];
    const float* b0  = (const float*)d_in[4];
    const float* W1  = (const float*)d_in[5];
    const float* b1  = (const float*)d_in[6];
    const float* W2  = (const float*)d_in[7];
    const float* b2  = (const float*)d_in[8];
    const float* lw  = (const float*)d_in[9];
    const float* lb  = (const float*)d_in[10];
    float* out = (float*)d_out;

    const int N = GCN_N;
    const int E = in_sizes[1] / 2;
    const int B = (E + CHUNK - 1) / CHUNK;

    char* ws = (char*)d_ws;
    size_t off = 0;
    auto alloc = [&](size_t bytes) {
        size_t o = off;
        off += (bytes + 255) & ~(size_t)255;
        return o;
    };
    int*   hist    = (int*)(ws + alloc((size_t)B * NBKT * 4));
    int*   offsT   = (int*)(ws + alloc((size_t)NBKT * B * 4));
    int*   btot    = (int*)(ws + alloc((size_t)NBKT * 4));
    int*   epack   = (int*)(ws + alloc((size_t)E * 4));
    int*   rowptr  = (int*)(ws + alloc((size_t)(N + 1) * 4));
    float* dis     = (float*)(ws + alloc((size_t)N * 4));
    int*   csrc    = (int*)(ws + alloc((size_t)E * 4));
    float* xsp     = (float*)(ws + alloc((size_t)N * 8 * 4));
    unsigned* t1q4 = (unsigned*)(ws + alloc((size_t)N * 64));   // 64 B/row fp4
    float* tscale  = (float*)(ws + alloc((size_t)N * 4));
    float* z       = (float*)(ws + alloc((size_t)N * 4));
    float* w2l     = (float*)(ws + alloc(128 * 4));
    float* c2      = (float*)(ws + alloc(4));
    unsigned short* w1t = (unsigned short*)(ws + alloc(128 * 128 * 2));
    float* gsum    = (float*)(ws + alloc(GCN_G * 4));   // gsum | gcnt | done contiguous
    int*   gcnt    = (int*)(ws + alloc(GCN_G * 4));
    int*   done    = (int*)(ws + alloc(4));

    const int* src = ei;
    const int* dst = ei + E;

    hipMemsetAsync(gsum, 0, GCN_G * 4 * 2 + 256, stream);   // gsum + gcnt + done

    hist_prep_kernel<<<B + 65, 256, 0, stream>>>(dst, hist, E, B, W1, W2, b2, lw, w1t, w2l, c2);
    scan_cols_kernel<<<NBKT, 64, 0, stream>>>(hist, offsT, btot, B);
    partition_kernel<<<B, 256, 0, stream>>>(src, dst, btot, offsT, epack, E, B);
    csr_build_kernel<<<NBKT, 512, 0, stream>>>(epack, btot, x, rowptr, dis, xsp, csrc, N);

    mmfused_kernel<<<(N + 127) / 128, 256, 0, stream>>>(xsp, rowptr, csrc, W0, b0, w1t, dis,
                                                        t1q4, tscale, N);
    agg1_kernel<<<(N + 15) / 16, 256, 0, stream>>>(t1q4, tscale, dis, rowptr, csrc, b1, w2l, z, N);
    aggz_pool_kernel<<<(N + 255) / 256, 256, 0, stream>>>(z, dis, rowptr, csrc, bat, c2, lb,
                                                          gsum, gcnt, done, out, N);
}